// Round 16
// baseline (305.898 us; speedup 1.0000x reference)
//
#include <hip/hip_runtime.h>
#include <stdint.h>

#define DIM 4096
#define NH 32
#define NKV 8
#define HD 128
#define SEQ 2048
#define KVD 1024  // NKV*HD

typedef unsigned short u16;
typedef __attribute__((ext_vector_type(8))) short bf16x8;   // 8 bf16 in 4 VGPRs
typedef __attribute__((ext_vector_type(4))) float f32x4;

__device__ __forceinline__ float bf2f(u16 v){
  union { unsigned u; float f; } c; c.u = ((unsigned)v) << 16; return c.f;
}
__device__ __forceinline__ u16 f2bf(float f){
  union { float f; unsigned u; } c; c.f = f;
  unsigned u = c.u;
  u += 0x7FFF + ((u >> 16) & 1);   // RNE
  return (u16)(u >> 16);
}
__device__ __forceinline__ unsigned pack2bf(float a, float b){
  return (unsigned)f2bf(a) | ((unsigned)f2bf(b) << 16);
}

__device__ __forceinline__ void gl_lds16(const void* g, void* l){
  __builtin_amdgcn_global_load_lds((const __attribute__((address_space(1))) void*)g,
                                   (__attribute__((address_space(3))) void*)l, 16, 0, 0);
}

#define VM0  asm volatile("s_waitcnt vmcnt(0)"  ::: "memory")
#define VM3  asm volatile("s_waitcnt vmcnt(3)"  ::: "memory")
#define VM4  asm volatile("s_waitcnt vmcnt(4)"  ::: "memory")
#define LGKM0 asm volatile("s_waitcnt lgkmcnt(0)" ::: "memory")
#define SB0 __builtin_amdgcn_sched_barrier(0)
#define BAR __builtin_amdgcn_s_barrier()

// ---------------- fused fp32 -> bf16 conversion (one launch, 5 segments) -----
__global__ void cvt_all(const float* __restrict__ x,  const float* __restrict__ wq,
                        const float* __restrict__ wk, const float* __restrict__ wv,
                        const float* __restrict__ wo,
                        u16* __restrict__ xb,  u16* __restrict__ wqb,
                        u16* __restrict__ wkb, u16* __restrict__ wvb,
                        u16* __restrict__ wob){
  const int b = blockIdx.x;
  const float* in; u16* out; int base;
  if      (b <  8192){ in = x;  out = xb;  base = b; }
  else if (b < 24576){ in = wq; out = wqb; base = b - 8192; }
  else if (b < 28672){ in = wk; out = wkb; base = b - 24576; }
  else if (b < 32768){ in = wv; out = wvb; base = b - 28672; }
  else               { in = wo; out = wob; base = b - 32768; }
  const int i = (base*256 + threadIdx.x)*4;
  float4 v = *(const float4*)(in + i);
  ushort4 o;
  o.x = f2bf(v.x); o.y = f2bf(v.y); o.z = f2bf(v.z); o.w = f2bf(v.w);
  *(ushort4*)(out + i) = o;
}

// ---------------- QKV: 2-phase, BM=128 x BN=192, 2 blocks/CU (R16) -----------
// gemmO skeleton with BUNITS=3. grid 512 = 16bm x 32bn (XCD-swizzled). 8 waves
// (2x4): wave owns 64 rows x 48 cols (acc[4][3]). 80 KB dbuf LDS ->
// EXACTLY 2 blocks/CU (160 KB): 16 waves/CU hide the barrier lockstep that
// capped the 1-block/CU variants at 40% MfmaUtil.
// P0 reads m-frags 0,1 + ALL B (held in regs); P1 reads m-frags 2,3.
// Staging: A(t+1) at P0(t) -> slot (t+1)&1 (that slot's A died after P1(t-1));
// B(t+2) at P1(t) -> slot t&1 (B(t) dead after P0(t): frags in regs).
// ONE wait/tile at end-P1(t): VM3 leaves exactly B(t+2)'s 3 loads in flight,
// drains A(t+1)+B(t+1) = all of tile t+1's reads. Tails: tt=nt-2 -> VM0;
// tt=nt-1 -> none. Prologue {B(0)x3, A(0)x2, B(1)x3; VM3} = steady history.
// EPI: route per 16-col frag: Q+RoPE (fc0<4096) / K+RoPE (<5120) / V^T.
__global__ __launch_bounds__(512, 2) void gemmQKV(const u16* __restrict__ A,
    const u16* __restrict__ B, void* __restrict__ C0, void* __restrict__ C1,
    void* __restrict__ C2, const float* __restrict__ rf){
  __shared__ __align__(16) char lds[81920];   // A[2][128][128B] | B[2][192][128B] at +32768
  const int t = threadIdx.x, w = t >> 6, l = t & 63;
  const int lg = l >> 4, li = l & 15;
  const int wr = w >> 2, wc = w & 3;
  const int idx = ((int)blockIdx.x & 7)*64 + ((int)blockIdx.x >> 3);  // XCD swizzle (nwg=512)
  const int bm = idx & 15, bn = idx >> 4;      // 16 x 32
  const int nt = 64;
  const u16* Ab = A + (size_t)bm*128*DIM;
  const u16* Bb = B + (size_t)bn*192*DIM;

  auto stA2 = [&](int k0, int slot){           // both A units (128 rows): 2 loads
    #pragma unroll
    for (int j = 0; j < 2; ++j){
      const int r = j*64 + (t >> 3);
      gl_lds16(Ab + (size_t)r*DIM + k0 + (((t & 7) ^ (r & 7)) << 3),
               lds + slot*16384 + r*128 + (t & 7)*16);
    }
  };
  auto stB1 = [&](int k0, int slot, int u){    // one B unit (64 rows): 1 load
    const int r = u*64 + (t >> 3);
    gl_lds16(Bb + (size_t)r*DIM + k0 + (((t & 7) ^ (r & 7)) << 3),
             lds + 32768 + slot*24576 + r*128 + (t & 7)*16);
  };

  f32x4 acc[4][3] = {};
  bf16x8 bfr[3][2];

#define PHQ(p, ...) { \
    bf16x8 af[2][2]; \
    _Pragma("unroll") \
    for (int q = 0; q < 2; ++q){ \
      const int R = wr*64 + (2*(p)+q)*16 + li; \
      af[q][0] = *(const bf16x8*)(ldsA + R*128 + (( lg    ^ (R & 7)) << 4)); \
      af[q][1] = *(const bf16x8*)(ldsA + R*128 + (((lg+4) ^ (R & 7)) << 4)); \
    } \
    if ((p) == 0){ \
      _Pragma("unroll") \
      for (int j = 0; j < 3; ++j){ \
        const int R = wc*48 + j*16 + li; \
        bfr[j][0] = *(const bf16x8*)(ldsB + R*128 + (( lg    ^ (R & 7)) << 4)); \
        bfr[j][1] = *(const bf16x8*)(ldsB + R*128 + (((lg+4) ^ (R & 7)) << 4)); \
      } \
    } \
    __VA_ARGS__; \
    BAR; LGKM0; SB0; \
    __builtin_amdgcn_s_setprio(1); \
    _Pragma("unroll") \
    for (int q = 0; q < 2; ++q) \
      _Pragma("unroll") \
      for (int j = 0; j < 3; ++j){ \
        acc[2*(p)+q][j] = __builtin_amdgcn_mfma_f32_16x16x32_bf16(af[q][0], bfr[j][0], acc[2*(p)+q][j], 0, 0, 0); \
        acc[2*(p)+q][j] = __builtin_amdgcn_mfma_f32_16x16x32_bf16(af[q][1], bfr[j][1], acc[2*(p)+q][j], 0, 0, 0); \
      } \
    __builtin_amdgcn_s_setprio(0); \
    BAR; }

  // prologue: B(0)x3, A(0)x2, B(1)x3 -> VM3 drains B(0),A(0); leaves B(1)
  #pragma unroll
  for (int u = 0; u < 3; ++u) stB1(0, 0, u);
  stA2(0, 0);
  #pragma unroll
  for (int u = 0; u < 3; ++u) stB1(64, 1, u);
  VM3; BAR;

  for (int tt = 0; tt < nt; ++tt){
    const char* ldsA = lds + (tt & 1)*16384;
    const char* ldsB = lds + 32768 + (tt & 1)*24576;
    const int k1 = (tt+1)*64, k2 = (tt+2)*64;

    PHQ(0, if (tt+1 < nt){ stA2(k1, (tt+1) & 1); })
    PHQ(1, if (tt+2 < nt){ stB1(k2, tt & 1, 0); stB1(k2, tt & 1, 1); stB1(k2, tt & 1, 2); }
           if (tt+1 < nt){ if (tt+2 < nt){ VM3; } else { VM0; } } )
  }
#undef PHQ

  // epilogue: route per 16-col frag (Q+RoPE / K+RoPE / V^T)
  #pragma unroll
  for (int i = 0; i < 4; ++i){
    const int srow0 = bm*128 + wr*64 + i*16 + lg*4;
    #pragma unroll
    for (int j = 0; j < 3; ++j){
      const int fc0 = bn*192 + wc*48 + j*16;   // frag base col (16-aligned)
      const int col = fc0 + li;
      if (fc0 < 5120){                   // Q (cols<4096) or K: fused RoPE
        u16* C  = (fc0 < 4096) ? (u16*)C0 : (u16*)C1;
        const int ldc  = (fc0 < 4096) ? DIM : KVD;
        const int ccol = (fc0 < 4096) ? col : col - 4096;
        const int i4 = ((col & 127) >> 1) << 2;        // boundaries %128==0
        #pragma unroll
        for (int r = 0; r < 4; ++r){
          const float v = acc[i][j][r];
          const float p = __shfl_xor(v, 1);            // partner col (li^1)
          const int srow = srow0 + r;
          const float cs = rf[(size_t)srow*256 + i4];
          const float sn = rf[(size_t)srow*256 + i4 + 1];
          const float o = (col & 1) ? (v*cs + p*sn) : (v*cs - p*sn);
          C[(size_t)srow*ldc + ccol] = f2bf(o);
        }
      } else {                           // V -> transposed write Vt[1024][2048]
        u16* C = (u16*)C2;
        ushort4 o;
        o.x = f2bf(acc[i][j][0]); o.y = f2bf(acc[i][j][1]);
        o.z = f2bf(acc[i][j][2]); o.w = f2bf(acc[i][j][3]);
        *(ushort4*)&C[(size_t)(col - 5120)*SEQ + srow0] = o;
      }
    }
  }
}

// ---------------- O-proj: BM=128 x BN=256, full K, no split-K (R15) ----------
// grid 256 = 16bm x 16bn (XCD-swizzled). 8 waves (2x4); wave owns 64x64.
// 2 phases/K-tile; 96 KB dbuf LDS. One VM4/tile (see R15 derivation).
__global__ __launch_bounds__(512, 1) void gemmO(const u16* __restrict__ A,
    const u16* __restrict__ B, float* __restrict__ C){
  __shared__ __align__(16) char lds[98304];   // A: [2][128][128B] | B at +32768
  const int t = threadIdx.x, w = t >> 6, l = t & 63;
  const int lg = l >> 4, li = l & 15;
  const int wr = w >> 2, wc = w & 3;
  const int idx = ((int)blockIdx.x & 7)*32 + ((int)blockIdx.x >> 3);  // XCD swizzle
  const int bm = idx & 15, bn = idx >> 4;
  const int nt = 64;
  const u16* Ab = A + (size_t)bm*128*DIM;
  const u16* Bb = B + (size_t)bn*256*DIM;

  auto stA2 = [&](int k0, int slot){        // both A units (128 rows), 2 loads
    #pragma unroll
    for (int j = 0; j < 2; ++j){
      const int r = j*64 + (t >> 3);
      gl_lds16(Ab + (size_t)r*DIM + k0 + (((t & 7) ^ (r & 7)) << 3),
               lds + slot*16384 + r*128 + (t & 7)*16);
    }
  };
  auto stB1 = [&](int k0, int slot, int u){ // one B unit (64 rows), 1 load
    const int r = u*64 + (t >> 3);
    gl_lds16(Bb + (size_t)r*DIM + k0 + (((t & 7) ^ (r & 7)) << 3),
             lds + 32768 + slot*32768 + r*128 + (t & 7)*16);
  };

  f32x4 acc[4][4] = {};
  bf16x8 bfr[4][2];

#define PHO(p, ...) { \
    bf16x8 af[2][2]; \
    _Pragma("unroll") \
    for (int q = 0; q < 2; ++q){ \
      const int R = wr*64 + (2*(p)+q)*16 + li; \
      af[q][0] = *(const bf16x8*)(ldsA + R*128 + (( lg    ^ (R & 7)) << 4)); \
      af[q][1] = *(const bf16x8*)(ldsA + R*128 + (((lg+4) ^ (R & 7)) << 4)); \
    } \
    if ((p) == 0){ \
      _Pragma("unroll") \
      for (int j = 0; j < 4; ++j){ \
        const int R = wc*64 + j*16 + li; \
        bfr[j][0] = *(const bf16x8*)(ldsB + R*128 + (( lg    ^ (R & 7)) << 4)); \
        bfr[j][1] = *(const bf16x8*)(ldsB + R*128 + (((lg+4) ^ (R & 7)) << 4)); \
      } \
    } \
    __VA_ARGS__; \
    BAR; LGKM0; SB0; \
    __builtin_amdgcn_s_setprio(1); \
    _Pragma("unroll") \
    for (int q = 0; q < 2; ++q) \
      _Pragma("unroll") \
      for (int j = 0; j < 4; ++j){ \
        acc[2*(p)+q][j] = __builtin_amdgcn_mfma_f32_16x16x32_bf16(af[q][0], bfr[j][0], acc[2*(p)+q][j], 0, 0, 0); \
        acc[2*(p)+q][j] = __builtin_amdgcn_mfma_f32_16x16x32_bf16(af[q][1], bfr[j][1], acc[2*(p)+q][j], 0, 0, 0); \
      } \
    __builtin_amdgcn_s_setprio(0); \
    BAR; }

  // prologue: B(0) x4, A(0), B(1) x4  -> VM4 drains A(0),B(0); leaves B(1)
  #pragma unroll
  for (int u = 0; u < 4; ++u) stB1(0, 0, u);
  stA2(0, 0);
  #pragma unroll
  for (int u = 0; u < 4; ++u) stB1(64, 1, u);
  VM4; BAR;

  for (int tt = 0; tt < nt; ++tt){
    const char* ldsA = lds + (tt & 1)*16384;
    const char* ldsB = lds + 32768 + (tt & 1)*32768;
    const int k1 = (tt+1)*64, k2 = (tt+2)*64;

    PHO(0, if (tt+1 < nt){ stA2(k1, (tt+1) & 1); })
    PHO(1, if (tt+2 < nt){ stB1(k2, tt & 1, 0); stB1(k2, tt & 1, 1);
                           stB1(k2, tt & 1, 2); stB1(k2, tt & 1, 3); }
           if (tt+1 < nt){ if (tt+2 < nt){ VM4; } else { VM0; } } )
  }
#undef PHO

  // epilogue: f32 direct
  #pragma unroll
  for (int i = 0; i < 4; ++i){
    const int srow = bm*128 + wr*64 + i*16 + lg*4;
    #pragma unroll
    for (int j = 0; j < 4; ++j){
      const int col = bn*256 + wc*64 + j*16 + li;
      #pragma unroll
      for (int r = 0; r < 4; ++r)
        C[(size_t)(srow + r)*DIM + col] = acc[i][j][r];
    }
  }
}

// ---------------- causal GQA flash attention (R13-proven: T13 + T5) ----------
// 1D grid 1024, longest-qt blocks first: qt = 31 - bid/32, h = bid%32.
// 4 waves; wave w owns q rows [qt*64+16w, +16). Swapped QK^T (mfma(K,Q)) so
// each lane owns one full q-row (q = li): in-lane softmax + 2-shfl reduce.
// K/V double-buffered in LDS, next tile staged before compute.
__global__ __launch_bounds__(256) void flash_attn(const u16* __restrict__ Q,
                                                  const u16* __restrict__ Kg,
                                                  const u16* __restrict__ Vt,
                                                  u16* __restrict__ O){
  __shared__ bf16x8 smK[2][64*16];              // [64 rows][16 slots], swizzled; 2x16KB
  __shared__ bf16x8 smV[2][128*8];              // [128 rows][8 slots], swizzled; 2x16KB
  __shared__ __align__(16) u16 smP[4][16*64];   // per-wave P, XOR-swizzled 16B chunks; 8KB
  const int bid = blockIdx.x;
  const int h  = bid & 31;
  const int qt = 31 - (bid >> 5);
  const int g  = h >> 2;
  const int t = threadIdx.x, w = t >> 6, l = t & 63;
  const int lg = l >> 4, li = l & 15;

  bf16x8 qf[4];                                  // Q row (w*16+li), d-chunks
  {
    const u16* qrow = Q + (size_t)(qt*64 + w*16 + li)*DIM + h*HD;
    #pragma unroll
    for (int kc = 0; kc < 4; ++kc)
      qf[kc] = *(const bf16x8*)(qrow + kc*32 + lg*8);
  }
  f32x4 accO[8] = {};
  float mrun = -1e30f, lsum = 0.f;
  const float SC = 0.08838834764831845f * 1.4426950408889634f;  // scale * log2(e)

  const int ksrow = t >> 4, ksslot = t & 15;  // K staging: 256B rows, 16 slots
  const int vsrow = t >> 3, vsslot = t & 7;   // V staging: 128B rows, 8 slots

  auto stage = [&](int kt, int b){
    #pragma unroll
    for (int j = 0; j < 4; ++j){
      const int krow = j*16 + ksrow;
      const int ksl = (ksslot & 8) | ((ksslot ^ (krow & 7)) & 7);
      gl_lds16(Kg + (size_t)(kt*64 + krow)*KVD + g*HD + ksl*8, (char*)&smK[b][0] + j*4096 + w*1024);
      const int vrow = j*32 + vsrow;
      const int vsl = (vsslot ^ (vrow & 7)) & 7;
      gl_lds16(Vt + (size_t)(g*HD + vrow)*SEQ + kt*64 + vsl*8, (char*)&smV[b][0] + j*4096 + w*1024);
    }
  };

  stage(0, 0);
  int buf = 0;
  u16* pw = &smP[w][0];

  for (int kt = 0; kt <= qt; ++kt){
    __syncthreads();                      // implicit vmcnt(0): tile-kt stage done
    if (kt < qt) stage(kt + 1, buf ^ 1);  // overlap next stage with this compute

    // S^T = K Q^T : lane holds S[kk = nj*16+lg*4+r][q = li]
    f32x4 sacc[4] = {};
    __builtin_amdgcn_s_setprio(1);
    #pragma unroll
    for (int kc = 0; kc < 4; ++kc){
      #pragma unroll
      for (int nj = 0; nj < 4; ++nj){
        const int R = nj*16 + li;
        int sl = lg + 4*kc;
        sl = (sl & 8) | ((sl ^ (R & 7)) & 7);
        sacc[nj] = __builtin_amdgcn_mfma_f32_16x16x32_bf16(smK[buf][R*16 + sl], qf[kc], sacc[nj], 0, 0, 0);
      }
    }
    __builtin_amdgcn_s_setprio(0);
    float p[4][4];
    #pragma unroll
    for (int nj = 0; nj < 4; ++nj)
      #pragma unroll
      for (int r = 0; r < 4; ++r)
        p[nj][r] = sacc[nj][r] * SC;
    if (kt == qt){                         // mask only on the diagonal tile
      const int qloc = w*16 + li;
      #pragma unroll
      for (int nj = 0; nj < 4; ++nj)
        #pragma unroll
        for (int r = 0; r < 4; ++r)
          if (nj*16 + lg*4 + r > qloc) p[nj][r] = -1e30f;
    }
    // online softmax, row q=li fully in this lane (16 vals) + lanes l^16,l^32
    float mx = p[0][0];
    #pragma unroll
    for (int nj = 0; nj < 4; ++nj)
      #pragma unroll
      for (int r = 0; r < 4; ++r) mx = fmaxf(mx, p[nj][r]);
    mx = fmaxf(mx, __shfl_xor(mx, 16));
    mx = fmaxf(mx, __shfl_xor(mx, 32));
    // T13 defer-max: skip rescale while max growth <= 8 (log2 units)
    if (!__all(mx - mrun <= 8.f)){
      const float mnew = fmaxf(mrun, mx);
      const float alpha = exp2f(mrun - mnew);
      lsum *= alpha;
      float al[4];
      #pragma unroll
      for (int r = 0; r < 4; ++r) al[r] = __shfl(alpha, (l & 48) | (lg*4 + r));
      #pragma unroll
      for (int dj = 0; dj < 8; ++dj)
        #pragma unroll
        for (int r = 0; r < 4; ++r) accO[dj][r] *= al[r];
      mrun = mnew;
    }
    float s = 0.f;
    #pragma unroll
    for (int nj = 0; nj < 4; ++nj)
      #pragma unroll
      for (int r = 0; r < 4; ++r){ p[nj][r] = exp2f(p[nj][r] - mrun); s += p[nj][r]; }
    s += __shfl_xor(s, 16);
    s += __shfl_xor(s, 32);
    lsum += s;
    // write P (row q=li, kk consecutive per write): 4x 8B swizzled ds_write
    #pragma unroll
    for (int nj = 0; nj < 4; ++nj){
      const int c = nj*2 + (lg >> 1);
      uint2 v; v.x = pack2bf(p[nj][0], p[nj][1]); v.y = pack2bf(p[nj][2], p[nj][3]);
      *(uint2*)((char*)pw + li*128 + ((c ^ (li & 7)) << 4) + ((lg & 1) << 3)) = v;
    }
    // O += P V   (A-frag: P row li, kk = kc2*32+lg*8+j; B-frag: Vt row d)
    __builtin_amdgcn_s_setprio(1);
    #pragma unroll
    for (int kc2 = 0; kc2 < 2; ++kc2){
      const bf16x8 pf = *(const bf16x8*)((char*)pw + li*128 + (((kc2*4 + lg) ^ (li & 7)) << 4));
      #pragma unroll
      for (int dj = 0; dj < 8; ++dj){
        const int R = dj*16 + li;
        const bf16x8 vf = smV[buf][R*8 + ((lg + 4*kc2) ^ (R & 7))];
        accO[dj] = __builtin_amdgcn_mfma_f32_16x16x32_bf16(pf, vf, accO[dj], 0, 0, 0);
      }
    }
    __builtin_amdgcn_s_setprio(0);
    buf ^= 1;
  }
  // epilogue: divide by row sum (row q=lg*4+r), write
  float linv[4];
  #pragma unroll
  for (int r = 0; r < 4; ++r) linv[r] = 1.f / __shfl(lsum, (l & 48) | (lg*4 + r));
  #pragma unroll
  for (int dj = 0; dj < 8; ++dj)
    #pragma unroll
    for (int r = 0; r < 4; ++r)
      O[(size_t)(qt*64 + w*16 + lg*4 + r)*DIM + h*HD + dj*16 + li] = f2bf(accO[dj][r] * linv[r]);
}

// -----------------------------------------------------------------------------
extern "C" void kernel_launch(void* const* d_in, const int* in_sizes, int n_in,
                              void* d_out, int out_size, void* d_ws, size_t ws_size,
                              hipStream_t stream){
  const float* x  = (const float*)d_in[0];
  const float* wq = (const float*)d_in[1];
  const float* wk = (const float*)d_in[2];
  const float* wv = (const float*)d_in[3];
  const float* wo = (const float*)d_in[4];
  const float* rf = (const float*)d_in[5];
  // d_in[6] = start_pos (unused by the reference)
  float* out = (float*)d_out;

  char* ws = (char*)d_ws;
  size_t off = 0;
  auto alloc = [&](size_t nbytes){ void* p = ws + off; off += (nbytes + 255) & ~(size_t)255; return p; };
  u16* xb  = (u16*)alloc((size_t)SEQ*DIM*2);
  u16* wqb = (u16*)alloc((size_t)DIM*DIM*2);   // wqb/wkb/wvb contiguous => B[6144][4096]
  u16* wkb = (u16*)alloc((size_t)KVD*DIM*2);
  u16* wvb = (u16*)alloc((size_t)KVD*DIM*2);
  u16* wob = (u16*)alloc((size_t)DIM*DIM*2);
  u16* Qb  = (u16*)alloc((size_t)SEQ*DIM*2);
  u16* K8  = (u16*)alloc((size_t)SEQ*KVD*2);
  u16* Vtr = (u16*)alloc((size_t)KVD*SEQ*2);
  u16* AO  = (u16*)alloc((size_t)SEQ*DIM*2);

  cvt_all<<<49152, 256, 0, stream>>>(x, wq, wk, wv, wo, xb, wqb, wkb, wvb, wob);

  // Fused QKV projection + RoPE + V^T: 512 blocks (16bm x 32bn), 2 blocks/CU
  gemmQKV<<<512, 512, 0, stream>>>(xb, wqb, Qb, K8, Vtr, rf);

  // Flash attention: 1024 blocks (32 qt x 32 heads), longest-first
  flash_attn<<<SEQ/64 * NH, 256, 0, stream>>>(Qb, K8, Vtr, AO);

  // O projection: BM=128 x BN=256, full K, no split-K (256 blocks), f32 out
  gemmO<<<256, 512, 0, stream>>>(AO, wob, out);
}

// Round 17
// 296.278 us; speedup vs baseline: 1.0325x; 1.0325x over previous
//
#include <hip/hip_runtime.h>
#include <stdint.h>

#define DIM 4096
#define NH 32
#define NKV 8
#define HD 128
#define SEQ 2048
#define KVD 1024  // NKV*HD

typedef unsigned short u16;
typedef __attribute__((ext_vector_type(8))) short bf16x8;   // 8 bf16 in 4 VGPRs
typedef __attribute__((ext_vector_type(4))) float f32x4;

__device__ __forceinline__ float bf2f(u16 v){
  union { unsigned u; float f; } c; c.u = ((unsigned)v) << 16; return c.f;
}
__device__ __forceinline__ u16 f2bf(float f){
  union { float f; unsigned u; } c; c.f = f;
  unsigned u = c.u;
  u += 0x7FFF + ((u >> 16) & 1);   // RNE
  return (u16)(u >> 16);
}
__device__ __forceinline__ unsigned pack2bf(float a, float b){
  return (unsigned)f2bf(a) | ((unsigned)f2bf(b) << 16);
}

__device__ __forceinline__ void gl_lds16(const void* g, void* l){
  __builtin_amdgcn_global_load_lds((const __attribute__((address_space(1))) void*)g,
                                   (__attribute__((address_space(3))) void*)l, 16, 0, 0);
}

#define VM0  asm volatile("s_waitcnt vmcnt(0)"  ::: "memory")
#define VM2  asm volatile("s_waitcnt vmcnt(2)"  ::: "memory")
#define VM4  asm volatile("s_waitcnt vmcnt(4)"  ::: "memory")
#define VM7  asm volatile("s_waitcnt vmcnt(7)"  ::: "memory")
#define VM10 asm volatile("s_waitcnt vmcnt(10)" ::: "memory")
#define LGKM0 asm volatile("s_waitcnt lgkmcnt(0)" ::: "memory")
#define SB0 __builtin_amdgcn_sched_barrier(0)
#define BAR __builtin_amdgcn_s_barrier()

// ---------------- fused fp32 -> bf16 conversion (one launch, 5 segments) -----
__global__ void cvt_all(const float* __restrict__ x,  const float* __restrict__ wq,
                        const float* __restrict__ wk, const float* __restrict__ wv,
                        const float* __restrict__ wo,
                        u16* __restrict__ xb,  u16* __restrict__ wqb,
                        u16* __restrict__ wkb, u16* __restrict__ wvb,
                        u16* __restrict__ wob){
  const int b = blockIdx.x;
  const float* in; u16* out; int base;
  if      (b <  8192){ in = x;  out = xb;  base = b; }
  else if (b < 24576){ in = wq; out = wqb; base = b - 8192; }
  else if (b < 28672){ in = wk; out = wkb; base = b - 24576; }
  else if (b < 32768){ in = wv; out = wvb; base = b - 28672; }
  else               { in = wo; out = wob; base = b - 32768; }
  const int i = (base*256 + threadIdx.x)*4;
  float4 v = *(const float4*)(in + i);
  ushort4 o;
  o.x = f2bf(v.x); o.y = f2bf(v.y); o.z = f2bf(v.z); o.w = f2bf(v.w);
  *(ushort4*)(out + i) = o;
}

// ---------------- QKV: 4-phase pipelined NT GEMM, 2-tiles-ahead (R14) ---------
// BM=256, BN=192 (BUNITS=3), BK=64, 8 waves (2x4), dbuf LDS. Liveness-based
// deep prefetch, counted waits VM10/VM7/VM2/VM0 (>=5-phase slack), 2 waits/tile.
// EPI: fused QKV (B=[wq;wk;wv] [6144][4096]): RoPE on Q/K cols, V^T write.
template<int BUNITS>
__global__ __launch_bounds__(512, 2) void gemmP(const u16* __restrict__ A,
    const u16* __restrict__ B, void* __restrict__ C0, void* __restrict__ C1,
    void* __restrict__ C2, const float* __restrict__ rf){
  constexpr int BN = BUNITS*64;
  __shared__ __align__(16) char lds[65536 + BUNITS*16384];  // A[2][256][128B] | B[2][BN][128B]
  const int t = threadIdx.x, w = t >> 6, l = t & 63;
  const int lg = l >> 4, li = l & 15;
  const int wr = w >> 2, wc = w & 3;
  const int idx = ((int)blockIdx.x & 7)*32 + ((int)blockIdx.x >> 3);  // XCD swizzle (nwg=256)
  const int bm = idx & 7, bn = idx >> 3;
  const int nt = 64, kbase = 0;
  const u16* Ab = A + (size_t)bm*256*DIM;
  const u16* Bb = B + (size_t)bn*BN*DIM;

  auto stA = [&](int k0, int abase, int u){
    const int r = u*64 + (t >> 3);
    gl_lds16(Ab + (size_t)r*DIM + k0 + (((t & 7) ^ (r & 7)) << 3),
             lds + abase + u*8192 + (t >> 3)*128 + (t & 7)*16);
  };
  auto stB = [&](int k0, int bbase, int u){
    const int r = u*64 + (t >> 3);
    gl_lds16(Bb + (size_t)r*DIM + k0 + (((t & 7) ^ (r & 7)) << 3),
             lds + bbase + u*8192 + (t >> 3)*128 + (t & 7)*16);
  };

  f32x4 acc[8][BUNITS] = {};
  bf16x8 bfr[BUNITS][2];   // B-frags held across all 4 phases of a tile

#define PH(p, ...) { \
    bf16x8 af[2][2]; \
    _Pragma("unroll") \
    for (int q = 0; q < 2; ++q){ \
      const int R = wr*128 + (2*(p)+q)*16 + li; \
      af[q][0] = *(const bf16x8*)(ldsA + R*128 + (( lg    ^ (R & 7)) << 4)); \
      af[q][1] = *(const bf16x8*)(ldsA + R*128 + (((lg+4) ^ (R & 7)) << 4)); \
    } \
    if ((p) == 0){ \
      _Pragma("unroll") \
      for (int j = 0; j < BUNITS; ++j){ \
        const int R = wc*(BUNITS*16) + j*16 + li; \
        bfr[j][0] = *(const bf16x8*)(ldsB + R*128 + (( lg    ^ (R & 7)) << 4)); \
        bfr[j][1] = *(const bf16x8*)(ldsB + R*128 + (((lg+4) ^ (R & 7)) << 4)); \
      } \
    } \
    __VA_ARGS__; \
    BAR; LGKM0; SB0; \
    __builtin_amdgcn_s_setprio(1); \
    _Pragma("unroll") \
    for (int q = 0; q < 2; ++q) \
      _Pragma("unroll") \
      for (int j = 0; j < BUNITS; ++j){ \
        acc[2*(p)+q][j] = __builtin_amdgcn_mfma_f32_16x16x32_bf16(af[q][0], bfr[j][0], acc[2*(p)+q][j], 0, 0, 0); \
        acc[2*(p)+q][j] = __builtin_amdgcn_mfma_f32_16x16x32_bf16(af[q][1], bfr[j][1], acc[2*(p)+q][j], 0, 0, 0); \
      } \
    __builtin_amdgcn_s_setprio(0); \
    BAR; }

  // prologue = steady-state issue history: B*(0),A0A2(0),A1A3(0),B*(1),A0A2(1)
  #pragma unroll
  for (int u = 0; u < BUNITS; ++u) stB(kbase, 65536, u);
  stA(kbase, 0, 0); stA(kbase, 0, 2);
  stA(kbase, 0, 1); stA(kbase, 0, 3);
  #pragma unroll
  for (int u = 0; u < BUNITS; ++u) stB(kbase + 64, 65536 + BUNITS*8192, u);
  stA(kbase + 64, 32768, 0); stA(kbase + 64, 32768, 2);
  VM7;   // drain through A0A2(0)  (BUNITS==3)
  BAR;

  for (int tt = 0; tt < nt; ++tt){
    const int k1 = kbase + (tt+1)*64, k2 = kbase + (tt+2)*64;
    const char* ldsA = lds + (tt & 1)*32768;
    const char* ldsB = lds + 65536 + (tt & 1)*BUNITS*8192;
    const int aCur = (tt & 1)*32768;                      // A(t+2) units 0,2 dest
    const int aNxt = ((tt+1) & 1)*32768;                  // A(t+1) units 1,3 dest
    const int bCur = 65536 + (tt & 1)*BUNITS*8192;        // B(t+2) dest (dead after P0)

    PH(0, if (tt+1 < nt){ stA(k1, aNxt, 1); stA(k1, aNxt, 3); })
    PH(1, if (tt+2 < nt){ _Pragma("unroll")
                          for (int u = 0; u < BUNITS; ++u) stB(k2, bCur, u); }
          if (tt == nt-1){ VM0; }
          else if (tt == nt-2){ VM7; }
          else { VM10; } )
    PH(2, if (tt+2 < nt){ stA(k2, aCur, 0); stA(k2, aCur, 2); })
    PH(3, if (tt+1 < nt){
            if (tt+1 == nt-1){ VM2; }
            else { VM7; }
          } )
  }
#undef PH

  // ---------------- epilogue: route per 16-col frag (Q+RoPE / K+RoPE / V^T) --
  #pragma unroll
  for (int i = 0; i < 8; ++i){
    const int srow0 = bm*256 + wr*128 + i*16 + lg*4;
    #pragma unroll
    for (int j = 0; j < BUNITS; ++j){
      const int fc0 = bn*BN + wc*(BUNITS*16) + j*16;   // frag base col (16-aligned)
      const int col = fc0 + li;
      if (fc0 < 5120){                   // Q (cols<4096) or K: fused RoPE
        u16* C  = (fc0 < 4096) ? (u16*)C0 : (u16*)C1;
        const int ldc  = (fc0 < 4096) ? DIM : KVD;
        const int ccol = (fc0 < 4096) ? col : col - 4096;
        const int i4 = ((col & 127) >> 1) << 2;        // boundaries %128==0
        #pragma unroll
        for (int r = 0; r < 4; ++r){
          const float v = acc[i][j][r];
          const float p = __shfl_xor(v, 1);            // partner col (li^1)
          const int srow = srow0 + r;
          const float cs = rf[(size_t)srow*256 + i4];
          const float sn = rf[(size_t)srow*256 + i4 + 1];
          const float o = (col & 1) ? (v*cs + p*sn) : (v*cs - p*sn);
          C[(size_t)srow*ldc + ccol] = f2bf(o);
        }
      } else {                           // V -> transposed write Vt[1024][2048]
        u16* C = (u16*)C2;
        ushort4 o;
        o.x = f2bf(acc[i][j][0]); o.y = f2bf(acc[i][j][1]);
        o.z = f2bf(acc[i][j][2]); o.w = f2bf(acc[i][j][3]);
        *(ushort4*)&C[(size_t)(col - 5120)*SEQ + srow0] = o;
      }
    }
  }
}

// ---------------- O-proj: BM=128 x BN=256, full K, no split-K (R15) ----------
// grid 256 = 16bm x 16bn (XCD-swizzled). 8 waves (2x4); wave owns 64x64.
// 2 phases/K-tile; 96 KB dbuf LDS. One VM4/tile (liveness-derived; R15 notes).
__global__ __launch_bounds__(512, 1) void gemmO(const u16* __restrict__ A,
    const u16* __restrict__ B, float* __restrict__ C){
  __shared__ __align__(16) char lds[98304];   // A: [2][128][128B] | B at +32768
  const int t = threadIdx.x, w = t >> 6, l = t & 63;
  const int lg = l >> 4, li = l & 15;
  const int wr = w >> 2, wc = w & 3;
  const int idx = ((int)blockIdx.x & 7)*32 + ((int)blockIdx.x >> 3);  // XCD swizzle
  const int bm = idx & 15, bn = idx >> 4;
  const int nt = 64;
  const u16* Ab = A + (size_t)bm*128*DIM;
  const u16* Bb = B + (size_t)bn*256*DIM;

  auto stA2 = [&](int k0, int slot){        // both A units (128 rows), 2 loads
    #pragma unroll
    for (int j = 0; j < 2; ++j){
      const int r = j*64 + (t >> 3);
      gl_lds16(Ab + (size_t)r*DIM + k0 + (((t & 7) ^ (r & 7)) << 3),
               lds + slot*16384 + r*128 + (t & 7)*16);
    }
  };
  auto stB1 = [&](int k0, int slot, int u){ // one B unit (64 rows), 1 load
    const int r = u*64 + (t >> 3);
    gl_lds16(Bb + (size_t)r*DIM + k0 + (((t & 7) ^ (r & 7)) << 3),
             lds + 32768 + slot*32768 + r*128 + (t & 7)*16);
  };

  f32x4 acc[4][4] = {};
  bf16x8 bfr[4][2];

#define PHO(p, ...) { \
    bf16x8 af[2][2]; \
    _Pragma("unroll") \
    for (int q = 0; q < 2; ++q){ \
      const int R = wr*64 + (2*(p)+q)*16 + li; \
      af[q][0] = *(const bf16x8*)(ldsA + R*128 + (( lg    ^ (R & 7)) << 4)); \
      af[q][1] = *(const bf16x8*)(ldsA + R*128 + (((lg+4) ^ (R & 7)) << 4)); \
    } \
    if ((p) == 0){ \
      _Pragma("unroll") \
      for (int j = 0; j < 4; ++j){ \
        const int R = wc*64 + j*16 + li; \
        bfr[j][0] = *(const bf16x8*)(ldsB + R*128 + (( lg    ^ (R & 7)) << 4)); \
        bfr[j][1] = *(const bf16x8*)(ldsB + R*128 + (((lg+4) ^ (R & 7)) << 4)); \
      } \
    } \
    __VA_ARGS__; \
    BAR; LGKM0; SB0; \
    __builtin_amdgcn_s_setprio(1); \
    _Pragma("unroll") \
    for (int q = 0; q < 2; ++q) \
      _Pragma("unroll") \
      for (int j = 0; j < 4; ++j){ \
        acc[2*(p)+q][j] = __builtin_amdgcn_mfma_f32_16x16x32_bf16(af[q][0], bfr[j][0], acc[2*(p)+q][j], 0, 0, 0); \
        acc[2*(p)+q][j] = __builtin_amdgcn_mfma_f32_16x16x32_bf16(af[q][1], bfr[j][1], acc[2*(p)+q][j], 0, 0, 0); \
      } \
    __builtin_amdgcn_s_setprio(0); \
    BAR; }

  // prologue: B(0) x4, A(0), B(1) x4  -> VM4 drains A(0),B(0); leaves B(1)
  #pragma unroll
  for (int u = 0; u < 4; ++u) stB1(0, 0, u);
  stA2(0, 0);
  #pragma unroll
  for (int u = 0; u < 4; ++u) stB1(64, 1, u);
  VM4; BAR;

  for (int tt = 0; tt < nt; ++tt){
    const char* ldsA = lds + (tt & 1)*16384;
    const char* ldsB = lds + 32768 + (tt & 1)*32768;
    const int k1 = (tt+1)*64, k2 = (tt+2)*64;

    PHO(0, if (tt+1 < nt){ stA2(k1, (tt+1) & 1); })
    PHO(1, if (tt+2 < nt){ stB1(k2, tt & 1, 0); stB1(k2, tt & 1, 1);
                           stB1(k2, tt & 1, 2); stB1(k2, tt & 1, 3); }
           if (tt+1 < nt){ if (tt+2 < nt){ VM4; } else { VM0; } } )
  }
#undef PHO

  // epilogue: f32 direct
  #pragma unroll
  for (int i = 0; i < 4; ++i){
    const int srow = bm*128 + wr*64 + i*16 + lg*4;
    #pragma unroll
    for (int j = 0; j < 4; ++j){
      const int col = bn*256 + wc*64 + j*16 + li;
      #pragma unroll
      for (int r = 0; r < 4; ++r)
        C[(size_t)(srow + r)*DIM + col] = acc[i][j][r];
    }
  }
}

// ---------------- causal GQA flash attention (R13-proven: T13 + T5) ----------
// 1D grid 1024, longest-qt blocks first: qt = 31 - bid/32, h = bid%32.
// 4 waves; wave w owns q rows [qt*64+16w, +16). Swapped QK^T (mfma(K,Q)) so
// each lane owns one full q-row (q = li): in-lane softmax + 2-shfl reduce.
// K/V double-buffered in LDS, next tile staged before compute.
__global__ __launch_bounds__(256) void flash_attn(const u16* __restrict__ Q,
                                                  const u16* __restrict__ Kg,
                                                  const u16* __restrict__ Vt,
                                                  u16* __restrict__ O){
  __shared__ bf16x8 smK[2][64*16];              // [64 rows][16 slots], swizzled; 2x16KB
  __shared__ bf16x8 smV[2][128*8];              // [128 rows][8 slots], swizzled; 2x16KB
  __shared__ __align__(16) u16 smP[4][16*64];   // per-wave P, XOR-swizzled 16B chunks; 8KB
  const int bid = blockIdx.x;
  const int h  = bid & 31;
  const int qt = 31 - (bid >> 5);
  const int g  = h >> 2;
  const int t = threadIdx.x, w = t >> 6, l = t & 63;
  const int lg = l >> 4, li = l & 15;

  bf16x8 qf[4];                                  // Q row (w*16+li), d-chunks
  {
    const u16* qrow = Q + (size_t)(qt*64 + w*16 + li)*DIM + h*HD;
    #pragma unroll
    for (int kc = 0; kc < 4; ++kc)
      qf[kc] = *(const bf16x8*)(qrow + kc*32 + lg*8);
  }
  f32x4 accO[8] = {};
  float mrun = -1e30f, lsum = 0.f;
  const float SC = 0.08838834764831845f * 1.4426950408889634f;  // scale * log2(e)

  const int ksrow = t >> 4, ksslot = t & 15;  // K staging: 256B rows, 16 slots
  const int vsrow = t >> 3, vsslot = t & 7;   // V staging: 128B rows, 8 slots

  auto stage = [&](int kt, int b){
    #pragma unroll
    for (int j = 0; j < 4; ++j){
      const int krow = j*16 + ksrow;
      const int ksl = (ksslot & 8) | ((ksslot ^ (krow & 7)) & 7);
      gl_lds16(Kg + (size_t)(kt*64 + krow)*KVD + g*HD + ksl*8, (char*)&smK[b][0] + j*4096 + w*1024);
      const int vrow = j*32 + vsrow;
      const int vsl = (vsslot ^ (vrow & 7)) & 7;
      gl_lds16(Vt + (size_t)(g*HD + vrow)*SEQ + kt*64 + vsl*8, (char*)&smV[b][0] + j*4096 + w*1024);
    }
  };

  stage(0, 0);
  int buf = 0;
  u16* pw = &smP[w][0];

  for (int kt = 0; kt <= qt; ++kt){
    __syncthreads();                      // implicit vmcnt(0): tile-kt stage done
    if (kt < qt) stage(kt + 1, buf ^ 1);  // overlap next stage with this compute

    // S^T = K Q^T : lane holds S[kk = nj*16+lg*4+r][q = li]
    f32x4 sacc[4] = {};
    __builtin_amdgcn_s_setprio(1);
    #pragma unroll
    for (int kc = 0; kc < 4; ++kc){
      #pragma unroll
      for (int nj = 0; nj < 4; ++nj){
        const int R = nj*16 + li;
        int sl = lg + 4*kc;
        sl = (sl & 8) | ((sl ^ (R & 7)) & 7);
        sacc[nj] = __builtin_amdgcn_mfma_f32_16x16x32_bf16(smK[buf][R*16 + sl], qf[kc], sacc[nj], 0, 0, 0);
      }
    }
    __builtin_amdgcn_s_setprio(0);
    float p[4][4];
    #pragma unroll
    for (int nj = 0; nj < 4; ++nj)
      #pragma unroll
      for (int r = 0; r < 4; ++r)
        p[nj][r] = sacc[nj][r] * SC;
    if (kt == qt){                         // mask only on the diagonal tile
      const int qloc = w*16 + li;
      #pragma unroll
      for (int nj = 0; nj < 4; ++nj)
        #pragma unroll
        for (int r = 0; r < 4; ++r)
          if (nj*16 + lg*4 + r > qloc) p[nj][r] = -1e30f;
    }
    // online softmax, row q=li fully in this lane (16 vals) + lanes l^16,l^32
    float mx = p[0][0];
    #pragma unroll
    for (int nj = 0; nj < 4; ++nj)
      #pragma unroll
      for (int r = 0; r < 4; ++r) mx = fmaxf(mx, p[nj][r]);
    mx = fmaxf(mx, __shfl_xor(mx, 16));
    mx = fmaxf(mx, __shfl_xor(mx, 32));
    // T13 defer-max: skip rescale while max growth <= 8 (log2 units)
    if (!__all(mx - mrun <= 8.f)){
      const float mnew = fmaxf(mrun, mx);
      const float alpha = exp2f(mrun - mnew);
      lsum *= alpha;
      float al[4];
      #pragma unroll
      for (int r = 0; r < 4; ++r) al[r] = __shfl(alpha, (l & 48) | (lg*4 + r));
      #pragma unroll
      for (int dj = 0; dj < 8; ++dj)
        #pragma unroll
        for (int r = 0; r < 4; ++r) accO[dj][r] *= al[r];
      mrun = mnew;
    }
    float s = 0.f;
    #pragma unroll
    for (int nj = 0; nj < 4; ++nj)
      #pragma unroll
      for (int r = 0; r < 4; ++r){ p[nj][r] = exp2f(p[nj][r] - mrun); s += p[nj][r]; }
    s += __shfl_xor(s, 16);
    s += __shfl_xor(s, 32);
    lsum += s;
    // write P (row q=li, kk consecutive per write): 4x 8B swizzled ds_write
    #pragma unroll
    for (int nj = 0; nj < 4; ++nj){
      const int c = nj*2 + (lg >> 1);
      uint2 v; v.x = pack2bf(p[nj][0], p[nj][1]); v.y = pack2bf(p[nj][2], p[nj][3]);
      *(uint2*)((char*)pw + li*128 + ((c ^ (li & 7)) << 4) + ((lg & 1) << 3)) = v;
    }
    // O += P V   (A-frag: P row li, kk = kc2*32+lg*8+j; B-frag: Vt row d)
    __builtin_amdgcn_s_setprio(1);
    #pragma unroll
    for (int kc2 = 0; kc2 < 2; ++kc2){
      const bf16x8 pf = *(const bf16x8*)((char*)pw + li*128 + (((kc2*4 + lg) ^ (li & 7)) << 4));
      #pragma unroll
      for (int dj = 0; dj < 8; ++dj){
        const int R = dj*16 + li;
        const bf16x8 vf = smV[buf][R*8 + ((lg + 4*kc2) ^ (R & 7))];
        accO[dj] = __builtin_amdgcn_mfma_f32_16x16x32_bf16(pf, vf, accO[dj], 0, 0, 0);
      }
    }
    __builtin_amdgcn_s_setprio(0);
    buf ^= 1;
  }
  // epilogue: divide by row sum (row q=lg*4+r), write
  float linv[4];
  #pragma unroll
  for (int r = 0; r < 4; ++r) linv[r] = 1.f / __shfl(lsum, (l & 48) | (lg*4 + r));
  #pragma unroll
  for (int dj = 0; dj < 8; ++dj)
    #pragma unroll
    for (int r = 0; r < 4; ++r)
      O[(size_t)(qt*64 + w*16 + lg*4 + r)*DIM + h*HD + dj*16 + li] = f2bf(accO[dj][r] * linv[r]);
}

// -----------------------------------------------------------------------------
extern "C" void kernel_launch(void* const* d_in, const int* in_sizes, int n_in,
                              void* d_out, int out_size, void* d_ws, size_t ws_size,
                              hipStream_t stream){
  const float* x  = (const float*)d_in[0];
  const float* wq = (const float*)d_in[1];
  const float* wk = (const float*)d_in[2];
  const float* wv = (const float*)d_in[3];
  const float* wo = (const float*)d_in[4];
  const float* rf = (const float*)d_in[5];
  // d_in[6] = start_pos (unused by the reference)
  float* out = (float*)d_out;

  char* ws = (char*)d_ws;
  size_t off = 0;
  auto alloc = [&](size_t nbytes){ void* p = ws + off; off += (nbytes + 255) & ~(size_t)255; return p; };
  u16* xb  = (u16*)alloc((size_t)SEQ*DIM*2);
  u16* wqb = (u16*)alloc((size_t)DIM*DIM*2);   // wqb/wkb/wvb contiguous => B[6144][4096]
  u16* wkb = (u16*)alloc((size_t)KVD*DIM*2);
  u16* wvb = (u16*)alloc((size_t)KVD*DIM*2);
  u16* wob = (u16*)alloc((size_t)DIM*DIM*2);
  u16* Qb  = (u16*)alloc((size_t)SEQ*DIM*2);
  u16* K8  = (u16*)alloc((size_t)SEQ*KVD*2);
  u16* Vtr = (u16*)alloc((size_t)KVD*SEQ*2);
  u16* AO  = (u16*)alloc((size_t)SEQ*DIM*2);

  cvt_all<<<49152, 256, 0, stream>>>(x, wq, wk, wv, wo, xb, wqb, wkb, wvb, wob);

  // Fused QKV projection + RoPE + V^T (256 blocks = 8bm x 32bn, BN=192)
  gemmP<3><<<256, 512, 0, stream>>>(xb, wqb, Qb, K8, Vtr, rf);

  // Flash attention: 1024 blocks (32 qt x 32 heads), longest-first
  flash_attn<<<SEQ/64 * NH, 256, 0, stream>>>(Qb, K8, Vtr, AO);

  // O projection: BM=128 x BN=256, full K, no split-K (256 blocks), f32 out
  gemmO<<<256, 512, 0, stream>>>(AO, wob, out);
}